// Round 16
// baseline (377.024 us; speedup 1.0000x reference)
//
#include <hip/hip_runtime.h>
#include <hip/hip_bf16.h>

#define HID 128
#define EXP 3
#define TOP 4
#define OUTC 64

typedef __bf16 bf16x8 __attribute__((ext_vector_type(8)));
typedef float f32x16 __attribute__((ext_vector_type(16)));
typedef float f32x2 __attribute__((ext_vector_type(2)));

#define GLDS_STRIDE 272              // staging: 128 bf16 = 256B + 16B pad
#define OUT_STRIDE 132               // out tile: 128 fp32 + 4 pad dwords

// fp8 e4m3 helpers (gfx950 HW cvt, OCP format; encode RNE)
__device__ __forceinline__ unsigned int pack4_fp8(float a, float b, float c, float d) {
    int v = 0;
    v = __builtin_amdgcn_cvt_pk_fp8_f32(a, b, v, false);   // bytes 0,1
    v = __builtin_amdgcn_cvt_pk_fp8_f32(c, d, v, true);    // bytes 2,3
    return (unsigned int)v;
}

__device__ __forceinline__ void unpack4_fp8(unsigned int v, float* out) {
    f32x2 lo = __builtin_amdgcn_cvt_pk_f32_fp8((int)v, false);
    f32x2 hi = __builtin_amdgcn_cvt_pk_f32_fp8((int)v, true);
    out[0] = lo[0]; out[1] = lo[1]; out[2] = hi[0]; out[3] = hi[1];
}

// ---------------- CSR build ----------------

// XCD-sliced count
__global__ void count_kernel(const int* __restrict__ dst, int* __restrict__ cnt, int E) {
    int slice = blockIdx.x & 7;
    int i = (blockIdx.x >> 3) * blockDim.x + threadIdx.x;
    if (i >= E) return;
    int d = dst[i];
    if (((d >> 6) & 7) != slice) return;
    atomicAdd(&cnt[d], 1);
}

// ---------------- hierarchical scan (dinv fused) ----------------

__global__ __launch_bounds__(256) void scan_local_kernel(const int* __restrict__ cnt,
                                                         int* __restrict__ row_ptr,
                                                         int* __restrict__ bsum,
                                                         float* __restrict__ dinv, int N) {
    __shared__ int sh[256];
    int b = blockIdx.x;
    int t = threadIdx.x;
    int base = b * 1024 + t * 4;
    int v[4] = {0, 0, 0, 0};
    if (base + 3 < N) {
        int4 c = *(const int4*)(cnt + base);
        v[0] = c.x; v[1] = c.y; v[2] = c.z; v[3] = c.w;
    } else {
#pragma unroll
        for (int k = 0; k < 4; ++k) if (base + k < N) v[k] = cnt[base + k];
    }
#pragma unroll
    for (int k = 0; k < 4; ++k)
        if (base + k < N) dinv[base + k] = rsqrtf((float)v[k] + 1.0f);
    int s = v[0] + v[1] + v[2] + v[3];
    sh[t] = s;
    __syncthreads();
    for (int off = 1; off < 256; off <<= 1) {
        int u = (t >= off) ? sh[t - off] : 0;
        __syncthreads();
        sh[t] += u;
        __syncthreads();
    }
    int run = sh[t] - s;
#pragma unroll
    for (int k = 0; k < 4; ++k) {
        if (base + k < N) row_ptr[base + k] = run;
        run += v[k];
    }
    if (t == 255) bsum[b] = sh[255];
}

__global__ __launch_bounds__(64) void scan_bsum_kernel(int* __restrict__ bsum, int nb,
                                                       int* __restrict__ total) {
    int t = threadIdx.x;
    int carry = 0;
    for (int base = 0; base < nb; base += 64) {
        int i = base + t;
        int v = (i < nb) ? bsum[i] : 0;
        int s = v;
#pragma unroll
        for (int off = 1; off < 64; off <<= 1) {
            int u = __shfl_up(s, off, 64);
            if (t >= off) s += u;
        }
        if (i < nb) bsum[i] = s - v + carry;
        carry += __shfl(s, 63, 64);
    }
    if (t == 0) *total = carry;
}

__global__ __launch_bounds__(256) void scan_fixup_kernel(const int* __restrict__ bsum,
                                                         const int* __restrict__ total,
                                                         int* __restrict__ row_ptr,
                                                         int* __restrict__ cursor, int N) {
    int b = blockIdx.x;
    int t = threadIdx.x;
    int off = bsum[b];
    int base = b * 1024 + t * 4;
#pragma unroll
    for (int k = 0; k < 4; ++k) {
        int i = base + k;
        if (i < N) {
            int r = row_ptr[i] + off;
            row_ptr[i] = r;
            cursor[i] = r;
        }
    }
    if (b == 0 && t == 0) row_ptr[N] = *total;
}

// XCD-sliced fill
__global__ void fill_kernel(const int* __restrict__ src, const int* __restrict__ dst,
                            int* __restrict__ cursor, const float* __restrict__ dinv,
                            int2* __restrict__ erec, int E) {
    int slice = blockIdx.x & 7;
    int i = (blockIdx.x >> 3) * blockDim.x + threadIdx.x;
    if (i >= E) return;
    int d = dst[i];
    if (((d >> 6) & 7) != slice) return;
    int s = src[i];
    int p = atomicAdd(&cursor[d], 1);
    erec[p] = make_int2(s, __float_as_int(dinv[s] * dinv[d]));
}

// ---------------- prep: gates + fp8 convert + find_starts (one dispatch) ----------------

__global__ __launch_bounds__(256) void prep_kernel(const float* __restrict__ tf,
                                                   const float* __restrict__ Wg0,
                                                   const float* __restrict__ Wg1,
                                                   float* __restrict__ gates,
                                                   const float* __restrict__ x,
                                                   unsigned int* __restrict__ x8,
                                                   const int* __restrict__ batch,
                                                   int* __restrict__ gstart,
                                                   int N, int G, int nConv, int nGate) {
    int b = blockIdx.x;
    if (b < nConv) {
        // fp8 convert of x
        int i = b * 256 + threadIdx.x;
        int total4 = N * HID / 4;
        if (i < total4) {
            float4 v = ((const float4*)x)[i];
            x8[i] = pack4_fp8(v.x, v.y, v.z, v.w);
        }
        return;
    }
    if (b < nConv + nGate) {
        int n = (b - nConv) * 256 + threadIdx.x;
        if (n >= N) return;
        float4 t = *(const float4*)(tf + (size_t)n * TOP);
        const float* Wg[2] = {Wg0, Wg1};
#pragma unroll
        for (int l = 0; l < 2; ++l) {
            float lg[EXP];
#pragma unroll
            for (int e = 0; e < EXP; ++e) {
                const float* w = Wg[l] + e * TOP;
                lg[e] = (t.x * w[0] + t.y * w[1] + t.z * w[2] + t.w * w[3]) * (1.0f / 101.0f);
            }
            float m = fmaxf(lg[0], fmaxf(lg[1], lg[2]));
            float e0 = expf(lg[0] - m), e1 = expf(lg[1] - m), e2 = expf(lg[2] - m);
            float inv = 1.0f / (e0 + e1 + e2);
            gates[n * 6 + l * 3 + 0] = e0 * inv;
            gates[n * 6 + l * 3 + 1] = e1 * inv;
            gates[n * 6 + l * 3 + 2] = e2 * inv;
        }
        return;
    }
    // find_starts (last block)
    int g = threadIdx.x;
    if (g > G) return;
    if (g == G) { gstart[G] = N; return; }
    int lo = 0, hi = N;
    while (lo < hi) {
        int mid = (lo + hi) >> 1;
        if (batch[mid] < g) lo = mid + 1; else hi = mid;
    }
    gstart[g] = lo;
}

// ---------------- W pack: B-fragment lane order, single bf16 ----------------

__global__ __launch_bounds__(64) void pack_w_kernel(const float* __restrict__ W0,
                                                    const float* __restrict__ W1,
                                                    __bf16* __restrict__ ph0,
                                                    __bf16* __restrict__ ph1) {
    int bid = blockIdx.x;           // 0..191
    int layer = bid / 96;
    int rem = bid % 96;
    int e = rem / 32;
    int s = (rem % 32) / 4;
    int c = rem % 4;
    const float* W = layer ? W1 : W0;
    __bf16* ph = layer ? ph1 : ph0;
    int l = threadIdx.x;
    size_t dstbase = (size_t)((((e * 8 + s) * 4 + c) * 64 + l)) * 8;
    int kbase = s * 16 + (l >> 5) * 8;
    int n = c * 32 + (l & 31);
#pragma unroll
    for (int j = 0; j < 8; ++j) {
        float w = W[(size_t)e * (HID * HID) + (size_t)(kbase + j) * HID + n];
        ph[dstbase + j] = (__bf16)w;
    }
}

// ---------------- aggregation: ag = A_hat @ h8, dwordx4 gathers ----------------
// 128 thr/node: thread t = (16B chunk t&7, edge slot t>>3) -> 16 slots,
// unroll 2 -> 32 edges in flight; 8 requests/edge (vs 16 before).

__global__ __launch_bounds__(128) void aggregate_kernel(const unsigned char* __restrict__ h8,
                                                        __bf16* __restrict__ aghi,
                                                        const int* __restrict__ row_ptr,
                                                        const int2* __restrict__ erec,
                                                        const float* __restrict__ dinv, int N) {
    __shared__ float red[2][HID];
    int n = blockIdx.x;
    int t = threadIdx.x;
    int c8 = t & 7;                 // 16B chunk within 128B row
    int slot = t >> 3;              // 0..15
    int s = row_ptr[n], e = row_ptr[n + 1];

    float acc[16];
#pragma unroll
    for (int j = 0; j < 16; ++j) acc[j] = 0.f;

    int i = s + slot;
    for (; i + 16 < e; i += 32) {
        int2 r0 = erec[i], r1 = erec[i + 16];
        float w0 = __int_as_float(r0.y), w1 = __int_as_float(r1.y);
        uint4 v0 = *(const uint4*)(h8 + (size_t)r0.x * HID + c8 * 16);
        uint4 v1 = *(const uint4*)(h8 + (size_t)r1.x * HID + c8 * 16);
        float f0[16], f1[16];
        unpack4_fp8(v0.x, f0);     unpack4_fp8(v0.y, f0 + 4);
        unpack4_fp8(v0.z, f0 + 8); unpack4_fp8(v0.w, f0 + 12);
        unpack4_fp8(v1.x, f1);     unpack4_fp8(v1.y, f1 + 4);
        unpack4_fp8(v1.z, f1 + 8); unpack4_fp8(v1.w, f1 + 12);
#pragma unroll
        for (int j = 0; j < 16; ++j)
            acc[j] += f0[j] * w0 + f1[j] * w1;
    }
    if (i < e) {
        int2 r0 = erec[i];
        float w0 = __int_as_float(r0.y);
        uint4 v0 = *(const uint4*)(h8 + (size_t)r0.x * HID + c8 * 16);
        float f0[16];
        unpack4_fp8(v0.x, f0);     unpack4_fp8(v0.y, f0 + 4);
        unpack4_fp8(v0.z, f0 + 8); unpack4_fp8(v0.w, f0 + 12);
#pragma unroll
        for (int j = 0; j < 16; ++j) acc[j] += f0[j] * w0;
    }

    // collapse 8 slots within each wave (slot = lane bits 3,4,5)
#pragma unroll
    for (int j = 0; j < 16; ++j) acc[j] += __shfl_xor(acc[j], 8, 64);
#pragma unroll
    for (int j = 0; j < 16; ++j) acc[j] += __shfl_xor(acc[j], 16, 64);
#pragma unroll
    for (int j = 0; j < 16; ++j) acc[j] += __shfl_xor(acc[j], 32, 64);

    int wv = t >> 6;
    int lane = t & 63;
    if (lane < 8) {
#pragma unroll
        for (int j = 0; j < 16; ++j) red[wv][lane * 16 + j] = acc[j];
    }
    __syncthreads();

    float dn = dinv[n];
    float self = __builtin_amdgcn_cvt_f32_fp8((int)h8[(size_t)n * HID + t], 0);
    float a = red[0][t] + red[1][t] + self * dn * dn;
    aghi[(size_t)n * HID + t] = (__bf16)a;
}

// ---------------- MFMA fused 3-expert GEMM + relu + gate ----------------

__global__ __launch_bounds__(256, 4) void expert_gemm_mfma_kernel(
        const __bf16* __restrict__ aghi,
        const __bf16* __restrict__ wpkh,
        const float* __restrict__ bias, const float* __restrict__ gates, int gate_off,
        unsigned char* __restrict__ hout8,
        const int* __restrict__ batch, float* __restrict__ pooled, int N) {
    __shared__ char lds[64 * OUT_STRIDE * 4];   // 33792 B; staging uses first 17408
    int tid = threadIdx.x;
    int row0 = blockIdx.x * 64;

#pragma unroll
    for (int it = 0; it < 4; ++it) {
        int id = tid + it * 256;
        int r = id >> 4;
        int c = id & 15;
        int gr = row0 + r;
        float4 vh = make_float4(0.f, 0.f, 0.f, 0.f);
        if (gr < N) vh = ((const float4*)aghi)[(size_t)gr * 16 + c];
        *(float4*)(lds + r * GLDS_STRIDE + c * 16) = vh;
    }
    __syncthreads();

    int lane = tid & 63;
    int wave = tid >> 6;
    int m = lane & 31;
    int g = lane >> 5;
    int rhalf = wave & 1;
    int chalf = wave >> 1;
    const char* arow = lds + (rhalf * 32 + m) * GLDS_STRIDE + g * 16;
    int rowbase = row0 + rhalf * 32 + 4 * g;

    float F[2][16];
#pragma unroll
    for (int c = 0; c < 2; ++c)
#pragma unroll
        for (int r = 0; r < 16; ++r) F[c][r] = 0.f;

    for (int e = 0; e < EXP; ++e) {
        f32x16 acc[2];
#pragma unroll
        for (int c = 0; c < 2; ++c)
#pragma unroll
            for (int r = 0; r < 16; ++r) acc[c][r] = 0.f;

#pragma unroll
        for (int s = 0; s < 8; ++s) {
            bf16x8 Ah = *(const bf16x8*)(arow + s * 32);
#pragma unroll
            for (int c = 0; c < 2; ++c) {
                int cp = chalf * 2 + c;
                bf16x8 Bh = *(const bf16x8*)(wpkh + (size_t)(((e * 8 + s) * 4 + cp) * 64 + lane) * 8);
                acc[c] = __builtin_amdgcn_mfma_f32_32x32x16_bf16(Ah, Bh, acc[c], 0, 0, 0);
            }
        }
        float gt[16];
#pragma unroll
        for (int r = 0; r < 16; ++r) {
            int rr = rowbase + (r & 3) + 8 * (r >> 2);
            gt[r] = (rr < N) ? gates[(size_t)rr * 6 + gate_off + e] : 0.f;
        }
#pragma unroll
        for (int c = 0; c < 2; ++c) {
            float bb = bias[e * HID + chalf * 64 + c * 32 + m];
#pragma unroll
            for (int r = 0; r < 16; ++r)
                F[c][r] += gt[r] * fmaxf(acc[c][r] + bb, 0.f);
        }
    }

    // ---- fragments -> LDS out-tile ----
    __syncthreads();
    float* lds32 = (float*)lds;
#pragma unroll
    for (int c = 0; c < 2; ++c) {
        int colg = chalf * 64 + c * 32 + m;
#pragma unroll
        for (int r = 0; r < 16; ++r) {
            int lr = rhalf * 32 + 4 * g + (r & 3) + 8 * (r >> 2);
            lds32[lr * OUT_STRIDE + colg] = F[c][r];
        }
    }
    __syncthreads();

    if (hout8) {
#pragma unroll
        for (int it = 0; it < 8; ++it) {
            int id = tid + it * 256;
            int r = id >> 5;
            int c4 = id & 31;
            int gr = row0 + r;
            if (gr < N) {
                const float* src = &lds32[r * OUT_STRIDE + c4 * 4];
                *(unsigned int*)(hout8 + (size_t)gr * HID + c4 * 4) =
                    pack4_fp8(src[0], src[1], src[2], src[3]);
            }
        }
    }
    if (pooled) {
        int col = tid & 127;
        int rbase = (tid >> 7) * 32;
        int cur = -1;
        float acc = 0.f;
        for (int r = 0; r < 32; ++r) {
            int gr = row0 + rbase + r;
            if (gr >= N) break;
            int gb = batch[gr];
            if (gb != cur) {
                if (cur >= 0) atomicAdd(&pooled[cur * HID + col], acc);
                acc = 0.f;
                cur = gb;
            }
            acc += lds32[(rbase + r) * OUT_STRIDE + col];
        }
        if (cur >= 0) atomicAdd(&pooled[cur * HID + col], acc);
    }
}

// ---------------- final ----------------

__global__ __launch_bounds__(64) void final_kernel(const float* __restrict__ pooled,
                                                   const int* __restrict__ gstart,
                                                   const float* __restrict__ Wf,
                                                   const float* __restrict__ bf,
                                                   float* __restrict__ out) {
    __shared__ float ps[HID];
    int g = blockIdx.x;
    int o = threadIdx.x;
    float invc = 1.0f / fmaxf((float)(gstart[g + 1] - gstart[g]), 1.0f);
    ps[o] = pooled[g * HID + o] * invc;
    ps[o + 64] = pooled[g * HID + o + 64] * invc;
    __syncthreads();
    float acc = bf[o];
#pragma unroll 8
    for (int k = 0; k < HID; ++k) acc = fmaf(ps[k], Wf[k * OUTC + o], acc);
    out[g * OUTC + o] = acc;
}

// ---------------- launch ----------------

extern "C" void kernel_launch(void* const* d_in, const int* in_sizes, int n_in,
                              void* d_out, int out_size, void* d_ws, size_t ws_size,
                              hipStream_t stream) {
    const float* x   = (const float*)d_in[0];
    const float* tf  = (const float*)d_in[1];
    const int*   ei  = (const int*)d_in[2];
    const int*   bat = (const int*)d_in[3];
    const float* W0  = (const float*)d_in[4];
    const float* b0  = (const float*)d_in[5];
    const float* Wg0 = (const float*)d_in[6];
    const float* W1  = (const float*)d_in[7];
    const float* b1  = (const float*)d_in[8];
    const float* Wg1 = (const float*)d_in[9];
    const float* Wf  = (const float*)d_in[10];
    const float* bf  = (const float*)d_in[11];
    float* out = (float*)d_out;

    const int N = in_sizes[0] / HID;       // 50000
    const int E = in_sizes[2] / 2;         // 800000
    const int G = out_size / OUTC;         // 64
    const int NB = (N + 1023) / 1024;

    char* p = (char*)d_ws;
    auto alloc = [&](size_t bytes) -> void* {
        void* r = (void*)p;
        p += (bytes + 255) & ~(size_t)255;
        return r;
    };
    float*         dinv   = (float*)alloc((size_t)N * 4);
    int*           cnt    = (int*)alloc((size_t)N * 4);
    int*           rowp   = (int*)alloc((size_t)(N + 1) * 4);
    int*           cursor = (int*)alloc((size_t)N * 4);
    float*         gates  = (float*)alloc((size_t)N * 6 * 4);
    int2*          erec   = (int2*)alloc((size_t)E * 8);
    __bf16*        aghi   = (__bf16*)alloc((size_t)N * HID * 2);
    unsigned char* h8     = (unsigned char*)alloc((size_t)N * HID);   // x8, then layer-1 h8
    int*           gstart = (int*)alloc((size_t)(G + 1) * 4);
    float*         pooled = (float*)alloc((size_t)G * HID * 4);
    int*           bsum   = (int*)alloc((size_t)NB * 4);
    int*           total  = (int*)alloc(4);
    __bf16*        wpkh0  = (__bf16*)alloc((size_t)EXP * HID * HID * 2);
    __bf16*        wpkh1  = (__bf16*)alloc((size_t)EXP * HID * HID * 2);

    const int* src = ei;
    const int* dst = ei + E;

    hipMemsetAsync(cnt, 0, (size_t)N * 4, stream);
    hipMemsetAsync(pooled, 0, (size_t)G * HID * 4, stream);

    const int nConv = (N * HID / 4 + 255) / 256;
    const int nGate = (N + 255) / 256;

    count_kernel<<<((E + 255) / 256) * 8, 256, 0, stream>>>(dst, cnt, E);
    scan_local_kernel<<<NB, 256, 0, stream>>>(cnt, rowp, bsum, dinv, N);
    scan_bsum_kernel<<<1, 64, 0, stream>>>(bsum, NB, total);
    scan_fixup_kernel<<<NB, 256, 0, stream>>>(bsum, total, rowp, cursor, N);
    fill_kernel<<<((E + 255) / 256) * 8, 256, 0, stream>>>(src, dst, cursor, dinv, erec, E);
    prep_kernel<<<nConv + nGate + 1, 256, 0, stream>>>(tf, Wg0, Wg1, gates,
                                                       x, (unsigned int*)h8,
                                                       bat, gstart, N, G, nConv, nGate);
    pack_w_kernel<<<192, 64, 0, stream>>>(W0, W1, wpkh0, wpkh1);

    int gemm_blocks = (N + 63) / 64;

    // layer 1: gather x8 -> ag; GEMM writes fp8 h
    aggregate_kernel<<<N, 128, 0, stream>>>(h8, aghi, rowp, erec, dinv, N);
    expert_gemm_mfma_kernel<<<gemm_blocks, 256, 0, stream>>>(aghi, wpkh0, b0, gates, 0,
                                                             h8, nullptr, nullptr, N);
    // layer 2: gather h8 -> ag; GEMM pools directly
    aggregate_kernel<<<N, 128, 0, stream>>>(h8, aghi, rowp, erec, dinv, N);
    expert_gemm_mfma_kernel<<<gemm_blocks, 256, 0, stream>>>(aghi, wpkh1, b1, gates, 3,
                                                             nullptr, bat, pooled, N);

    // final projection
    final_kernel<<<G, 64, 0, stream>>>(pooled, gstart, Wf, bf, out);
}

// Round 17
// 324.241 us; speedup vs baseline: 1.1628x; 1.1628x over previous
//
#include <hip/hip_runtime.h>
#include <hip/hip_bf16.h>

#define HID 128
#define EXP 3
#define TOP 4
#define OUTC 64

typedef __bf16 bf16x8 __attribute__((ext_vector_type(8)));
typedef float f32x16 __attribute__((ext_vector_type(16)));
typedef float f32x2 __attribute__((ext_vector_type(2)));

#define GLDS_STRIDE 272              // staging: 128 bf16 = 256B + 16B pad
#define OUT_STRIDE 132               // out tile: 128 fp32 + 4 pad dwords

// fp8 e4m3 helpers (gfx950 HW cvt, OCP format; encode RNE)
__device__ __forceinline__ unsigned int pack4_fp8(float a, float b, float c, float d) {
    int v = 0;
    v = __builtin_amdgcn_cvt_pk_fp8_f32(a, b, v, false);   // bytes 0,1
    v = __builtin_amdgcn_cvt_pk_fp8_f32(c, d, v, true);    // bytes 2,3
    return (unsigned int)v;
}

__device__ __forceinline__ void unpack4_fp8(unsigned int v, float* out) {
    f32x2 lo = __builtin_amdgcn_cvt_pk_f32_fp8((int)v, false);
    f32x2 hi = __builtin_amdgcn_cvt_pk_f32_fp8((int)v, true);
    out[0] = lo[0]; out[1] = lo[1]; out[2] = hi[0]; out[3] = hi[1];
}

// ---------------- CSR build ----------------

// XCD-sliced count
__global__ void count_kernel(const int* __restrict__ dst, int* __restrict__ cnt, int E) {
    int slice = blockIdx.x & 7;
    int i = (blockIdx.x >> 3) * blockDim.x + threadIdx.x;
    if (i >= E) return;
    int d = dst[i];
    if (((d >> 6) & 7) != slice) return;
    atomicAdd(&cnt[d], 1);
}

// ---------------- hierarchical scan (dinv fused) ----------------

__global__ __launch_bounds__(256) void scan_local_kernel(const int* __restrict__ cnt,
                                                         int* __restrict__ row_ptr,
                                                         int* __restrict__ bsum,
                                                         float* __restrict__ dinv, int N) {
    __shared__ int sh[256];
    int b = blockIdx.x;
    int t = threadIdx.x;
    int base = b * 1024 + t * 4;
    int v[4] = {0, 0, 0, 0};
    if (base + 3 < N) {
        int4 c = *(const int4*)(cnt + base);
        v[0] = c.x; v[1] = c.y; v[2] = c.z; v[3] = c.w;
    } else {
#pragma unroll
        for (int k = 0; k < 4; ++k) if (base + k < N) v[k] = cnt[base + k];
    }
#pragma unroll
    for (int k = 0; k < 4; ++k)
        if (base + k < N) dinv[base + k] = rsqrtf((float)v[k] + 1.0f);
    int s = v[0] + v[1] + v[2] + v[3];
    sh[t] = s;
    __syncthreads();
    for (int off = 1; off < 256; off <<= 1) {
        int u = (t >= off) ? sh[t - off] : 0;
        __syncthreads();
        sh[t] += u;
        __syncthreads();
    }
    int run = sh[t] - s;
#pragma unroll
    for (int k = 0; k < 4; ++k) {
        if (base + k < N) row_ptr[base + k] = run;
        run += v[k];
    }
    if (t == 255) bsum[b] = sh[255];
}

__global__ __launch_bounds__(64) void scan_bsum_kernel(int* __restrict__ bsum, int nb,
                                                       int* __restrict__ total) {
    int t = threadIdx.x;
    int carry = 0;
    for (int base = 0; base < nb; base += 64) {
        int i = base + t;
        int v = (i < nb) ? bsum[i] : 0;
        int s = v;
#pragma unroll
        for (int off = 1; off < 64; off <<= 1) {
            int u = __shfl_up(s, off, 64);
            if (t >= off) s += u;
        }
        if (i < nb) bsum[i] = s - v + carry;
        carry += __shfl(s, 63, 64);
    }
    if (t == 0) *total = carry;
}

__global__ __launch_bounds__(256) void scan_fixup_kernel(const int* __restrict__ bsum,
                                                         const int* __restrict__ total,
                                                         int* __restrict__ row_ptr,
                                                         int* __restrict__ cursor, int N) {
    int b = blockIdx.x;
    int t = threadIdx.x;
    int off = bsum[b];
    int base = b * 1024 + t * 4;
#pragma unroll
    for (int k = 0; k < 4; ++k) {
        int i = base + k;
        if (i < N) {
            int r = row_ptr[i] + off;
            row_ptr[i] = r;
            cursor[i] = r;
        }
    }
    if (b == 0 && t == 0) row_ptr[N] = *total;
}

// XCD-sliced fill
__global__ void fill_kernel(const int* __restrict__ src, const int* __restrict__ dst,
                            int* __restrict__ cursor, const float* __restrict__ dinv,
                            int2* __restrict__ erec, int E) {
    int slice = blockIdx.x & 7;
    int i = (blockIdx.x >> 3) * blockDim.x + threadIdx.x;
    if (i >= E) return;
    int d = dst[i];
    if (((d >> 6) & 7) != slice) return;
    int s = src[i];
    int p = atomicAdd(&cursor[d], 1);
    erec[p] = make_int2(s, __float_as_int(dinv[s] * dinv[d]));
}

// ---------------- prep: gates + fp8 convert + find_starts (one dispatch) ----------------

__global__ __launch_bounds__(256) void prep_kernel(const float* __restrict__ tf,
                                                   const float* __restrict__ Wg0,
                                                   const float* __restrict__ Wg1,
                                                   float* __restrict__ gates,
                                                   const float* __restrict__ x,
                                                   unsigned int* __restrict__ x8,
                                                   const int* __restrict__ batch,
                                                   int* __restrict__ gstart,
                                                   int N, int G, int nConv, int nGate) {
    int b = blockIdx.x;
    if (b < nConv) {
        int i = b * 256 + threadIdx.x;
        int total4 = N * HID / 4;
        if (i < total4) {
            float4 v = ((const float4*)x)[i];
            x8[i] = pack4_fp8(v.x, v.y, v.z, v.w);
        }
        return;
    }
    if (b < nConv + nGate) {
        int n = (b - nConv) * 256 + threadIdx.x;
        if (n >= N) return;
        float4 t = *(const float4*)(tf + (size_t)n * TOP);
        const float* Wg[2] = {Wg0, Wg1};
#pragma unroll
        for (int l = 0; l < 2; ++l) {
            float lg[EXP];
#pragma unroll
            for (int e = 0; e < EXP; ++e) {
                const float* w = Wg[l] + e * TOP;
                lg[e] = (t.x * w[0] + t.y * w[1] + t.z * w[2] + t.w * w[3]) * (1.0f / 101.0f);
            }
            float m = fmaxf(lg[0], fmaxf(lg[1], lg[2]));
            float e0 = expf(lg[0] - m), e1 = expf(lg[1] - m), e2 = expf(lg[2] - m);
            float inv = 1.0f / (e0 + e1 + e2);
            gates[n * 6 + l * 3 + 0] = e0 * inv;
            gates[n * 6 + l * 3 + 1] = e1 * inv;
            gates[n * 6 + l * 3 + 2] = e2 * inv;
        }
        return;
    }
    // find_starts (last block)
    int g = threadIdx.x;
    if (g > G) return;
    if (g == G) { gstart[G] = N; return; }
    int lo = 0, hi = N;
    while (lo < hi) {
        int mid = (lo + hi) >> 1;
        if (batch[mid] < g) lo = mid + 1; else hi = mid;
    }
    gstart[g] = lo;
}

// ---------------- W pack: B-fragment lane order, single bf16 ----------------

__global__ __launch_bounds__(64) void pack_w_kernel(const float* __restrict__ W0,
                                                    const float* __restrict__ W1,
                                                    __bf16* __restrict__ ph0,
                                                    __bf16* __restrict__ ph1) {
    int bid = blockIdx.x;           // 0..191
    int layer = bid / 96;
    int rem = bid % 96;
    int e = rem / 32;
    int s = (rem % 32) / 4;
    int c = rem % 4;
    const float* W = layer ? W1 : W0;
    __bf16* ph = layer ? ph1 : ph0;
    int l = threadIdx.x;
    size_t dstbase = (size_t)((((e * 8 + s) * 4 + c) * 64 + l)) * 8;
    int kbase = s * 16 + (l >> 5) * 8;
    int n = c * 32 + (l & 31);
#pragma unroll
    for (int j = 0; j < 8; ++j) {
        float w = W[(size_t)e * (HID * HID) + (size_t)(kbase + j) * HID + n];
        ph[dstbase + j] = (__bf16)w;
    }
}

// ---------------- aggregation (r15 shape, empirical optimum) ----------------
// 128 thr/node: thread t = (8B chunk t&15, edge slot t>>4); 8 slots, unroll 2
// -> 16 dwordx2 gathers in flight; shfl_xor(16/32) + 2-wave LDS combine.

__global__ __launch_bounds__(128) void aggregate_kernel(const unsigned char* __restrict__ h8,
                                                        __bf16* __restrict__ aghi,
                                                        const int* __restrict__ row_ptr,
                                                        const int2* __restrict__ erec,
                                                        const float* __restrict__ dinv, int N) {
    __shared__ float red[2][HID];
    int n = blockIdx.x;
    int t = threadIdx.x;
    int c16 = t & 15;
    int slot = t >> 4;              // 0..7
    int s = row_ptr[n], e = row_ptr[n + 1];

    float acc[8];
#pragma unroll
    for (int j = 0; j < 8; ++j) acc[j] = 0.f;

    int i = s + slot;
    for (; i + 8 < e; i += 16) {
        int2 r0 = erec[i], r1 = erec[i + 8];
        float w0 = __int_as_float(r0.y), w1 = __int_as_float(r1.y);
        uint2 v0 = *(const uint2*)(h8 + (size_t)r0.x * HID + c16 * 8);
        uint2 v1 = *(const uint2*)(h8 + (size_t)r1.x * HID + c16 * 8);
        float f0[8], f1[8];
        unpack4_fp8(v0.x, f0); unpack4_fp8(v0.y, f0 + 4);
        unpack4_fp8(v1.x, f1); unpack4_fp8(v1.y, f1 + 4);
#pragma unroll
        for (int j = 0; j < 8; ++j)
            acc[j] += f0[j] * w0 + f1[j] * w1;
    }
    if (i < e) {
        int2 r0 = erec[i];
        float w0 = __int_as_float(r0.y);
        uint2 v0 = *(const uint2*)(h8 + (size_t)r0.x * HID + c16 * 8);
        float f0[8];
        unpack4_fp8(v0.x, f0); unpack4_fp8(v0.y, f0 + 4);
#pragma unroll
        for (int j = 0; j < 8; ++j) acc[j] += f0[j] * w0;
    }

    // combine the 4 slots within each wave (lane^16, lane^32)
#pragma unroll
    for (int j = 0; j < 8; ++j) acc[j] += __shfl_xor(acc[j], 16, 64);
#pragma unroll
    for (int j = 0; j < 8; ++j) acc[j] += __shfl_xor(acc[j], 32, 64);

    int wv = t >> 6;
    int lane = t & 63;
    if (lane < 16) {
#pragma unroll
        for (int j = 0; j < 8; ++j) red[wv][lane * 8 + j] = acc[j];
    }
    __syncthreads();

    float dn = dinv[n];
    float self = __builtin_amdgcn_cvt_f32_fp8((int)h8[(size_t)n * HID + t], 0);
    float a = red[0][t] + red[1][t] + self * dn * dn;
    aghi[(size_t)n * HID + t] = (__bf16)a;
}

// ---------------- MFMA fused 3-expert GEMM + relu + gate ----------------

__global__ __launch_bounds__(256, 4) void expert_gemm_mfma_kernel(
        const __bf16* __restrict__ aghi,
        const __bf16* __restrict__ wpkh,
        const float* __restrict__ bias, const float* __restrict__ gates, int gate_off,
        unsigned char* __restrict__ hout8,
        const int* __restrict__ batch, float* __restrict__ pooled, int N) {
    __shared__ char lds[64 * OUT_STRIDE * 4];   // 33792 B; staging uses first 17408
    int tid = threadIdx.x;
    int row0 = blockIdx.x * 64;

#pragma unroll
    for (int it = 0; it < 4; ++it) {
        int id = tid + it * 256;
        int r = id >> 4;
        int c = id & 15;
        int gr = row0 + r;
        float4 vh = make_float4(0.f, 0.f, 0.f, 0.f);
        if (gr < N) vh = ((const float4*)aghi)[(size_t)gr * 16 + c];
        *(float4*)(lds + r * GLDS_STRIDE + c * 16) = vh;
    }
    __syncthreads();

    int lane = tid & 63;
    int wave = tid >> 6;
    int m = lane & 31;
    int g = lane >> 5;
    int rhalf = wave & 1;
    int chalf = wave >> 1;
    const char* arow = lds + (rhalf * 32 + m) * GLDS_STRIDE + g * 16;
    int rowbase = row0 + rhalf * 32 + 4 * g;

    float F[2][16];
#pragma unroll
    for (int c = 0; c < 2; ++c)
#pragma unroll
        for (int r = 0; r < 16; ++r) F[c][r] = 0.f;

    for (int e = 0; e < EXP; ++e) {
        f32x16 acc[2];
#pragma unroll
        for (int c = 0; c < 2; ++c)
#pragma unroll
            for (int r = 0; r < 16; ++r) acc[c][r] = 0.f;

#pragma unroll
        for (int s = 0; s < 8; ++s) {
            bf16x8 Ah = *(const bf16x8*)(arow + s * 32);
#pragma unroll
            for (int c = 0; c < 2; ++c) {
                int cp = chalf * 2 + c;
                bf16x8 Bh = *(const bf16x8*)(wpkh + (size_t)(((e * 8 + s) * 4 + cp) * 64 + lane) * 8);
                acc[c] = __builtin_amdgcn_mfma_f32_32x32x16_bf16(Ah, Bh, acc[c], 0, 0, 0);
            }
        }
        float gt[16];
#pragma unroll
        for (int r = 0; r < 16; ++r) {
            int rr = rowbase + (r & 3) + 8 * (r >> 2);
            gt[r] = (rr < N) ? gates[(size_t)rr * 6 + gate_off + e] : 0.f;
        }
#pragma unroll
        for (int c = 0; c < 2; ++c) {
            float bb = bias[e * HID + chalf * 64 + c * 32 + m];
#pragma unroll
            for (int r = 0; r < 16; ++r)
                F[c][r] += gt[r] * fmaxf(acc[c][r] + bb, 0.f);
        }
    }

    // ---- fragments -> LDS out-tile ----
    __syncthreads();
    float* lds32 = (float*)lds;
#pragma unroll
    for (int c = 0; c < 2; ++c) {
        int colg = chalf * 64 + c * 32 + m;
#pragma unroll
        for (int r = 0; r < 16; ++r) {
            int lr = rhalf * 32 + 4 * g + (r & 3) + 8 * (r >> 2);
            lds32[lr * OUT_STRIDE + colg] = F[c][r];
        }
    }
    __syncthreads();

    if (hout8) {
#pragma unroll
        for (int it = 0; it < 8; ++it) {
            int id = tid + it * 256;
            int r = id >> 5;
            int c4 = id & 31;
            int gr = row0 + r;
            if (gr < N) {
                const float* src = &lds32[r * OUT_STRIDE + c4 * 4];
                *(unsigned int*)(hout8 + (size_t)gr * HID + c4 * 4) =
                    pack4_fp8(src[0], src[1], src[2], src[3]);
            }
        }
    }
    if (pooled) {
        int col = tid & 127;
        int rbase = (tid >> 7) * 32;
        int cur = -1;
        float acc = 0.f;
        for (int r = 0; r < 32; ++r) {
            int gr = row0 + rbase + r;
            if (gr >= N) break;
            int gb = batch[gr];
            if (gb != cur) {
                if (cur >= 0) atomicAdd(&pooled[cur * HID + col], acc);
                acc = 0.f;
                cur = gb;
            }
            acc += lds32[(rbase + r) * OUT_STRIDE + col];
        }
        if (cur >= 0) atomicAdd(&pooled[cur * HID + col], acc);
    }
}

// ---------------- final ----------------

__global__ __launch_bounds__(64) void final_kernel(const float* __restrict__ pooled,
                                                   const int* __restrict__ gstart,
                                                   const float* __restrict__ Wf,
                                                   const float* __restrict__ bf,
                                                   float* __restrict__ out) {
    __shared__ float ps[HID];
    int g = blockIdx.x;
    int o = threadIdx.x;
    float invc = 1.0f / fmaxf((float)(gstart[g + 1] - gstart[g]), 1.0f);
    ps[o] = pooled[g * HID + o] * invc;
    ps[o + 64] = pooled[g * HID + o + 64] * invc;
    __syncthreads();
    float acc = bf[o];
#pragma unroll 8
    for (int k = 0; k < HID; ++k) acc = fmaf(ps[k], Wf[k * OUTC + o], acc);
    out[g * OUTC + o] = acc;
}

// ---------------- launch ----------------

extern "C" void kernel_launch(void* const* d_in, const int* in_sizes, int n_in,
                              void* d_out, int out_size, void* d_ws, size_t ws_size,
                              hipStream_t stream) {
    const float* x   = (const float*)d_in[0];
    const float* tf  = (const float*)d_in[1];
    const int*   ei  = (const int*)d_in[2];
    const int*   bat = (const int*)d_in[3];
    const float* W0  = (const float*)d_in[4];
    const float* b0  = (const float*)d_in[5];
    const float* Wg0 = (const float*)d_in[6];
    const float* W1  = (const float*)d_in[7];
    const float* b1  = (const float*)d_in[8];
    const float* Wg1 = (const float*)d_in[9];
    const float* Wf  = (const float*)d_in[10];
    const float* bf  = (const float*)d_in[11];
    float* out = (float*)d_out;

    const int N = in_sizes[0] / HID;       // 50000
    const int E = in_sizes[2] / 2;         // 800000
    const int G = out_size / OUTC;         // 64
    const int NB = (N + 1023) / 1024;

    char* p = (char*)d_ws;
    auto alloc = [&](size_t bytes) -> void* {
        void* r = (void*)p;
        p += (bytes + 255) & ~(size_t)255;
        return r;
    };
    float*         dinv   = (float*)alloc((size_t)N * 4);
    int*           cnt    = (int*)alloc((size_t)N * 4);
    int*           rowp   = (int*)alloc((size_t)(N + 1) * 4);
    int*           cursor = (int*)alloc((size_t)N * 4);
    float*         gates  = (float*)alloc((size_t)N * 6 * 4);
    int2*          erec   = (int2*)alloc((size_t)E * 8);
    __bf16*        aghi   = (__bf16*)alloc((size_t)N * HID * 2);
    unsigned char* h8     = (unsigned char*)alloc((size_t)N * HID);   // x8, then layer-1 h8
    int*           gstart = (int*)alloc((size_t)(G + 1) * 4);
    float*         pooled = (float*)alloc((size_t)G * HID * 4);
    int*           bsum   = (int*)alloc((size_t)NB * 4);
    int*           total  = (int*)alloc(4);
    __bf16*        wpkh0  = (__bf16*)alloc((size_t)EXP * HID * HID * 2);
    __bf16*        wpkh1  = (__bf16*)alloc((size_t)EXP * HID * HID * 2);

    const int* src = ei;
    const int* dst = ei + E;

    hipMemsetAsync(cnt, 0, (size_t)N * 4, stream);
    hipMemsetAsync(pooled, 0, (size_t)G * HID * 4, stream);

    const int nConv = (N * HID / 4 + 255) / 256;
    const int nGate = (N + 255) / 256;

    count_kernel<<<((E + 255) / 256) * 8, 256, 0, stream>>>(dst, cnt, E);
    scan_local_kernel<<<NB, 256, 0, stream>>>(cnt, rowp, bsum, dinv, N);
    scan_bsum_kernel<<<1, 64, 0, stream>>>(bsum, NB, total);
    scan_fixup_kernel<<<NB, 256, 0, stream>>>(bsum, total, rowp, cursor, N);
    fill_kernel<<<((E + 255) / 256) * 8, 256, 0, stream>>>(src, dst, cursor, dinv, erec, E);
    prep_kernel<<<nConv + nGate + 1, 256, 0, stream>>>(tf, Wg0, Wg1, gates,
                                                       x, (unsigned int*)h8,
                                                       bat, gstart, N, G, nConv, nGate);
    pack_w_kernel<<<192, 64, 0, stream>>>(W0, W1, wpkh0, wpkh1);

    int gemm_blocks = (N + 63) / 64;

    // layer 1: gather x8 -> ag; GEMM writes fp8 h
    aggregate_kernel<<<N, 128, 0, stream>>>(h8, aghi, rowp, erec, dinv, N);
    expert_gemm_mfma_kernel<<<gemm_blocks, 256, 0, stream>>>(aghi, wpkh0, b0, gates, 0,
                                                             h8, nullptr, nullptr, N);
    // layer 2: gather h8 -> ag; GEMM pools directly
    aggregate_kernel<<<N, 128, 0, stream>>>(h8, aghi, rowp, erec, dinv, N);
    expert_gemm_mfma_kernel<<<gemm_blocks, 256, 0, stream>>>(aghi, wpkh1, b1, gates, 3,
                                                             nullptr, bat, pooled, N);

    // final projection
    final_kernel<<<G, 64, 0, stream>>>(pooled, gstart, Wf, bf, out);
}